// Round 1
// baseline (261.235 us; speedup 1.0000x reference)
//
#include <hip/hip_runtime.h>
#include <math.h>

namespace {
constexpr int Bb = 32, Nn = 32, Ll = 512, Mm = 64, Ff = 64;
constexpr int TL = 32;          // L-tile
constexpr int BG = 4;           // batches per block
constexpr int NTILES = Ll / TL; // 16
constexpr float EPSV = 1e-8f;
}

__global__ __launch_bounds__(256, 1)
void wagg_kernel(const float* __restrict__ x_aug,
                 const float* __restrict__ t_in,
                 const float* __restrict__ t_left,
                 const float* __restrict__ t_right,
                 const float* __restrict__ kappa,
                 float* __restrict__ out)
{
    const int n   = blockIdx.x >> 3;        // 32 n values
    const int b0  = (blockIdx.x & 7) * BG;  // 8 b-groups of 4
    const int tid = threadIdx.x;

    __shared__ float xs[BG][TL][Ff];   // 32 KB  x tile
    __shared__ float as_[TL][Mm];      //  8 KB  alpha tile
    __shared__ float ts[Ll];           //  2 KB  t vector
    __shared__ float dred[4][Mm];      //  1 KB  denom reduce

    for (int i = tid; i < Ll; i += 256) ts[i] = t_in[i];

    // ---- alpha-producer role: fixed m = am, l stride 4 offset alq ----
    const int am  = tid & 63;
    const int alq = tid >> 6;
    const float kap = kappa[n];
    const float kk  = fmaxf(kap, 0.0f) + log1pf(expf(-fabsf(kap))); // softplus
    const float ik  = 1.0f / kk;
    const float tlv = t_left [n * Mm + am];
    const float trv = t_right[n * Mm + am];

    // ---- compute role: batch bs, 8m x 8f register tile ----
    const int bs   = tid >> 6;              // 0..3
    const int lane = tid & 63;
    const int mi   = (lane >> 3) << 3;      // 0,8,...,56
    const int fi   = (lane & 7) << 3;       // 0,8,...,56

    float acc[8][8];
    #pragma unroll
    for (int i = 0; i < 8; ++i)
        #pragma unroll
        for (int j = 0; j < 8; ++j) acc[i][j] = 0.0f;

    float4 stg[8];
    float  aval[8];
    float  dpart = 0.0f;

    __syncthreads();  // ts ready

    // ---- prologue: stage tile 0 ----
    {
        const int l0 = 0;
        #pragma unroll
        for (int k = 0; k < 8; ++k) {
            const int g   = k * 256 + tid;
            const int gbs = g >> 9;
            const int r   = (g >> 4) & 31;
            const int fq  = (g & 15) << 2;
            const float* src = x_aug
                + (size_t)((b0 + gbs) * Nn + n) * (Ll * Ff)
                + (size_t)(l0 + r) * Ff + fq;
            stg[k] = *(const float4*)src;
        }
        #pragma unroll
        for (int i = 0; i < 8; ++i) {
            const int ll = alq + (i << 2);
            const float tv = ts[l0 + ll];
            const float e1 = __expf((tv - trv) * ik);   // e^{-(tr-t)/k}
            const float e2 = __expf((tlv - tv) * ik);   // e^{-(t-tl)/k}
            const float a  = 1.0f / ((1.0f + e1) * (1.0f + e2));
            aval[i] = a;
            dpart += a;
        }
        #pragma unroll
        for (int k = 0; k < 8; ++k)
            ((float4*)xs)[k * 256 + tid] = stg[k];
        #pragma unroll
        for (int i = 0; i < 8; ++i)
            as_[alq + (i << 2)][am] = aval[i];
    }
    __syncthreads();

    for (int tile = 0; tile < NTILES; ++tile) {
        // prefetch next tile into registers (overlaps with FMA below)
        if (tile + 1 < NTILES) {
            const int l0 = (tile + 1) * TL;
            #pragma unroll
            for (int k = 0; k < 8; ++k) {
                const int g   = k * 256 + tid;
                const int gbs = g >> 9;
                const int r   = (g >> 4) & 31;
                const int fq  = (g & 15) << 2;
                const float* src = x_aug
                    + (size_t)((b0 + gbs) * Nn + n) * (Ll * Ff)
                    + (size_t)(l0 + r) * Ff + fq;
                stg[k] = *(const float4*)src;
            }
            #pragma unroll
            for (int i = 0; i < 8; ++i) {
                const int ll = alq + (i << 2);
                const float tv = ts[l0 + ll];
                const float e1 = __expf((tv - trv) * ik);
                const float e2 = __expf((tlv - tv) * ik);
                const float a  = 1.0f / ((1.0f + e1) * (1.0f + e2));
                aval[i] = a;
                dpart += a;
            }
        }
        // FMA on current LDS tile
        #pragma unroll 4
        for (int lt = 0; lt < TL; ++lt) {
            float av[8], xv[8];
            *(float4*)&av[0] = *(const float4*)&as_[lt][mi];
            *(float4*)&av[4] = *(const float4*)&as_[lt][mi + 4];
            *(float4*)&xv[0] = *(const float4*)&xs[bs][lt][fi];
            *(float4*)&xv[4] = *(const float4*)&xs[bs][lt][fi + 4];
            #pragma unroll
            for (int i = 0; i < 8; ++i)
                #pragma unroll
                for (int j = 0; j < 8; ++j)
                    acc[i][j] = fmaf(av[i], xv[j], acc[i][j]);
        }
        __syncthreads();
        if (tile + 1 < NTILES) {
            #pragma unroll
            for (int k = 0; k < 8; ++k)
                ((float4*)xs)[k * 256 + tid] = stg[k];
            #pragma unroll
            for (int i = 0; i < 8; ++i)
                as_[alq + (i << 2)][am] = aval[i];
        }
        __syncthreads();
    }

    // ---- denominator: sum 4 partials per m, invert once ----
    dred[alq][am] = dpart;
    __syncthreads();
    if (tid < Mm) {
        const float d = dred[0][tid] + dred[1][tid] + dred[2][tid] + dred[3][tid];
        dred[0][tid] = 1.0f / (d + EPSV);
    }
    __syncthreads();

    // ---- epilogue: normalize + store ----
    const size_t obase = ((size_t)(b0 + bs) * Nn + n) * Mm;
    #pragma unroll
    for (int i = 0; i < 8; ++i) {
        const float inv = dred[0][mi + i];
        float o[8];
        #pragma unroll
        for (int j = 0; j < 8; ++j) o[j] = acc[i][j] * inv;
        float* dst = out + (obase + (mi + i)) * Ff + fi;
        *(float4*)dst       = *(float4*)&o[0];
        *((float4*)dst + 1) = *(float4*)&o[4];
    }
}

extern "C" void kernel_launch(void* const* d_in, const int* in_sizes, int n_in,
                              void* d_out, int out_size, void* d_ws, size_t ws_size,
                              hipStream_t stream)
{
    const float* x_aug   = (const float*)d_in[0];
    const float* t_in    = (const float*)d_in[1];
    const float* t_left  = (const float*)d_in[2];
    const float* t_right = (const float*)d_in[3];
    const float* kappa   = (const float*)d_in[4];
    float* out = (float*)d_out;

    dim3 grid(Nn * (Bb / BG));   // 32 * 8 = 256 blocks, 1 per CU
    dim3 block(256);
    hipLaunchKernelGGL(wagg_kernel, grid, block, 0, stream,
                       x_aug, t_in, t_left, t_right, kappa, out);
}